// Round 2
// baseline (145.277 us; speedup 1.0000x reference)
//
#include <hip/hip_runtime.h>
#include <hip/hip_bf16.h>

#define VOCAB 100000
#define DIM   128
#define BATCH 16384
#define KNEG  20

// Half-wave (32 lanes) per batch row: lane sub holds float4 = row[4*sub..4*sub+3]
// (32 x 16B = 512 B = one full embedding row). Each 64-lane wave processes two
// rows (b0 = halves 0, b0+1 = half 1) simultaneously; the xor-butterfly with
// masks 1..16 never crosses the 32-lane half boundary, so one 5-step butterfly
// reduces both rows' scores at once.
__global__ __launch_bounds__(256) void skipgram_loss_kernel(
    const int*   __restrict__ target,
    const int*   __restrict__ context,
    const int*   __restrict__ neg_samples,
    const float* __restrict__ in_embed,
    const float* __restrict__ out_embed,
    float*       __restrict__ out)
{
    const int lane  = threadIdx.x & 63;
    const int half  = lane >> 5;        // 0 or 1: which row of the pair
    const int sub   = lane & 31;        // lane within the half
    const int wave  = threadIdx.x >> 6;
    const int wpb   = blockDim.x >> 6;  // 4 waves per block
    const int gwave = blockIdx.x * wpb + wave;
    const int nwav  = gridDim.x * wpb;

    float acc = 0.0f;  // becomes uniform within each 32-lane half

    for (int b0 = gwave * 2; b0 < BATCH; b0 += nwav * 2) {
        const int b    = b0 + half;     // BATCH is even; always in range
        const int trow = target[b];
        const int crow = context[b];

        const float4 t4 = *(const float4*)(in_embed  + (size_t)trow * DIM + sub * 4);
        const float4 c4 = *(const float4*)(out_embed + (size_t)crow * DIM + sub * 4);

        // Cooperative neg-index load: lanes sub<20 fetch the row's 20 indices
        // in one coalesced load; broadcast to the half via 32-wide shfl.
        const int myidx = (sub < KNEG) ? neg_samples[b * KNEG + sub] : 0;

        int nrow[KNEG];
        #pragma unroll
        for (int k = 0; k < KNEG; ++k)
            nrow[k] = __shfl(myidx, k, 32);   // within 32-lane group -> per-half

        float p[KNEG + 1];
        p[0] = t4.x * c4.x + t4.y * c4.y + t4.z * c4.z + t4.w * c4.w;

        #pragma unroll
        for (int k = 0; k < KNEG; ++k) {
            const float4 n4 = *(const float4*)(out_embed + (size_t)nrow[k] * DIM + sub * 4);
            p[k + 1] = t4.x * n4.x + t4.y * n4.y + t4.z * n4.z + t4.w * n4.w;
        }

        #pragma unroll
        for (int k = 0; k < KNEG + 1; ++k) {
            float v = p[k];
            #pragma unroll
            for (int m = 1; m < 32; m <<= 1)
                v += __shfl_xor(v, m, 64);    // masks <32: stays within the half
            // v = full dot for this half's row, uniform across its 32 lanes.
            const float x  = (k == 0) ? v : -v;   // pos: ls(s); neg: ls(-s)
            const float ls = fminf(x, 0.0f) - __logf(1.0f + __expf(-fabsf(x)));
            acc += ls;
        }
    }

    // acc is uniform within each 32-lane half; one contribution per half.
    __shared__ float smem[8];
    if (sub == 0) smem[wave * 2 + half] = acc;
    __syncthreads();
    if (threadIdx.x == 0) {
        float tot = 0.0f;
        for (int i = 0; i < wpb * 2; ++i) tot += smem[i];
        atomicAdd(out, -tot * (1.0f / (float)BATCH));
    }
}

extern "C" void kernel_launch(void* const* d_in, const int* in_sizes, int n_in,
                              void* d_out, int out_size, void* d_ws, size_t ws_size,
                              hipStream_t stream) {
    const int*   target      = (const int*)  d_in[0];
    const int*   context     = (const int*)  d_in[1];
    const int*   neg_samples = (const int*)  d_in[2];
    const float* in_embed    = (const float*)d_in[3];
    const float* out_embed   = (const float*)d_in[4];
    float*       out         = (float*)d_out;

    // d_out is poisoned (0xAA) before every launch — zero it (capture-safe).
    hipMemsetAsync(out, 0, sizeof(float), stream);

    // 2048 blocks x 4 waves = 8192 waves; each wave does one 2-row iteration.
    skipgram_loss_kernel<<<2048, 256, 0, stream>>>(
        target, context, neg_samples, in_embed, out_embed, out);
}